// Round 3
// baseline (795.562 us; speedup 1.0000x reference)
//
#include <hip/hip_runtime.h>

// Problem constants (fixed by setup_inputs)
#define BB 8
#define DD 32
#define HH 512
#define WW 512
#define HWSZ (HH*WW)          // 262144 = 2^18
#define NPIX (BB*HWSZ)        // 2097152
#define CC 19
#define EPSF 1e-8f

// Global accumulator layout: per class 65 floats:
// [0..31]=sum(x), [32..63]=sum(x/|x|), [64]=count
#define CSTRIDE 65
#define ACCSZ (CC*CSTRIDE)    // 1235 floats

// ---- k1 tiling ----
#define P 256                 // pixels per tile
#define XSTR 264              // LDS x-row stride (floats); 264%32==8 -> bank-rotated rows
#define NT1 256
#define NB1 1024              // 4 blocks/CU * 256 CUs
#define NTILES (NPIX/P)       // 8192
#define TPB (HWSZ/P)          // 1024 tiles per batch image
#define TILES_PER_BLK (NTILES/NB1)  // 8 (contiguous per block; b is constant per block)

// LDS layout (float offsets):
//   [0, 32*XSTR)   x tile (transposed [dim][pixel])
//   LX_INVN..+256  invn per pixel
//   LX_LABS..+256  labels (int)
// Epilogue reduction reuses sm as [256][39] -> needs 9984 floats = 39936 B -> 4 blocks/CU
#define LX_INVN (32*XSTR)         // 8448
#define LX_LABS (LX_INVN + P)     // 8704
#define LTOT 9984

__global__ void k0_zero(float* __restrict__ acc)
{
    int i = blockIdx.x * 256 + threadIdx.x;
    if (i < ACCSZ) acc[i] = 0.f;
}

// ---- tiny label histogram (counts) -> acc[c*65+64] ----
#define NCB 1024
__global__ __launch_bounds__(256) void k_count(const int* __restrict__ tgt,
                                               float* __restrict__ acc)
{
    __shared__ float h[32*20];   // 32 copies x 19 classes (stride 20)
    const int t = threadIdx.x;
    for (int i = t; i < 32*20; i += 256) h[i] = 0.f;
    __syncthreads();
    float* my = h + (t & 31) * 20;
    const int T = NCB * 256;                 // 262144 threads
    int tid = blockIdx.x * 256 + t;
    for (int i = tid; i < NPIX/4; i += T) {  // 2 iterations
        int4 lv = ((const int4*)tgt)[i];
        unsafeAtomicAdd(my + lv.x, 1.f);
        unsafeAtomicAdd(my + lv.y, 1.f);
        unsafeAtomicAdd(my + lv.z, 1.f);
        unsafeAtomicAdd(my + lv.w, 1.f);
    }
    __syncthreads();
    if (t < CC) {
        float s = 0.f;
        #pragma unroll
        for (int k = 0; k < 32; k++) s += h[k*20 + t];
        unsafeAtomicAdd(acc + t*CSTRIDE + 64, s);
    }
}

// per-element class-select accumulate: 1 cmp + 1 cndmask + 2 fma per class
#define PROC(XX, NN, LL)                                  \
    {                                                     \
        const float x_  = (XX);                           \
        const float xn_ = x_ * (NN);                      \
        const int   l_  = (LL);                           \
        _Pragma("unroll")                                 \
        for (int c = 0; c < CC; c++) {                    \
            const float m_ = (l_ == c) ? 1.0f : 0.0f;     \
            aS[c] = fmaf(m_, x_,  aS[c]);                 \
            aN[c] = fmaf(m_, xn_, aN[c]);                 \
        }                                                 \
    }

__global__ __launch_bounds__(NT1, 4) void k1_accum(
    const float* __restrict__ in, const int* __restrict__ tgt,
    float* __restrict__ acc)
{
    __shared__ __align__(16) float sm[LTOT];
    int* const smi = (int*)sm;
    const int t = threadIdx.x;

    // staging role: lane-local dim-group so the norm reduce stays in-wave
    const int w  = t >> 6;         // wave id: pixel group [w*64, w*64+64)
    const int l  = t & 63;
    const int dq = l & 3;          // dim group: dims [dq*8, dq*8+8)
    const int q  = l >> 2;         // 0..15 : pixel quad within wave group
    // phase-2 role
    const int d   = t >> 3;        // 0..31 : owned dim
    const int sub = t & 7;         // pixel sub-slice
    const float* xrow = sm + d * XSTR;

    float aS[CC], aN[CC];
    #pragma unroll
    for (int c = 0; c < CC; c++) { aS[c] = 0.f; aN[c] = 0.f; }

    const int tl0 = blockIdx.x * TILES_PER_BLK;
    const int b   = tl0 / TPB;               // constant per block (8 | 1024)
    const int hw0 = (tl0 % TPB) * P;

    const float* gx = in + ((size_t)(b*DD + dq*8))*HWSZ + hw0 + w*64 + 4*q;
    const int*   gl = tgt + (size_t)tl0*P + w*64 + 4*q;

    // prologue: issue loads for tile 0
    float4 X[8];
    int4 LB;
    #pragma unroll
    for (int dd = 0; dd < 8; dd++) X[dd] = *(const float4*)(gx + (size_t)dd*HWSZ);
    if (dq == 1) LB = *(const int4*)gl;

    for (int i = 0; i < TILES_PER_BLK; i++) {
        // --- per-pixel squared sums over this lane's 8 dims (registers only) ---
        float4 ss = make_float4(0.f, 0.f, 0.f, 0.f);
        #pragma unroll
        for (int dd = 0; dd < 8; dd++) {
            ss.x = fmaf(X[dd].x, X[dd].x, ss.x);
            ss.y = fmaf(X[dd].y, X[dd].y, ss.y);
            ss.z = fmaf(X[dd].z, X[dd].z, ss.z);
            ss.w = fmaf(X[dd].w, X[dd].w, ss.w);
        }
        // butterfly over the 4 dim-group lanes (l^1, l^2) -> full 32-dim sums
        ss.x += __shfl_xor(ss.x, 1); ss.y += __shfl_xor(ss.y, 1);
        ss.z += __shfl_xor(ss.z, 1); ss.w += __shfl_xor(ss.w, 1);
        ss.x += __shfl_xor(ss.x, 2); ss.y += __shfl_xor(ss.y, 2);
        ss.z += __shfl_xor(ss.z, 2); ss.w += __shfl_xor(ss.w, 2);
        float4 iv;
        iv.x = rsqrtf(fmaxf(ss.x, 1e-30f));
        iv.y = rsqrtf(fmaxf(ss.y, 1e-30f));
        iv.z = rsqrtf(fmaxf(ss.z, 1e-30f));
        iv.w = rsqrtf(fmaxf(ss.w, 1e-30f));

        __syncthreads();   // A: all waves done reading previous tile's LDS

        // --- write tile to LDS (transpose layout). b128 bank quads 2-way -> free ---
        #pragma unroll
        for (int dd = 0; dd < 8; dd++)
            *(float4*)(sm + (dq*8 + dd)*XSTR + w*64 + 4*q) = X[dd];
        if (dq == 0) *(float4*)(sm + LX_INVN + w*64 + 4*q) = iv;
        if (dq == 1) *(int4*)(smi + LX_LABS + w*64 + 4*q) = LB;

        __syncthreads();   // B: tile visible (lgkmcnt drained -> X regs reusable)

        // --- issue prefetch for next tile; latency hides under phase 2 ---
        if (i + 1 < TILES_PER_BLK) {
            gx += P; gl += P;
            #pragma unroll
            for (int dd = 0; dd < 8; dd++) X[dd] = *(const float4*)(gx + (size_t)dd*HWSZ);
            if (dq == 1) LB = *(const int4*)gl;
        }

        // --- phase 2: per-(d,sub) register accumulation, 19-way select ---
        #pragma unroll 2
        for (int k = 0; k < P/32; k++) {
            const int p0 = 4*sub + 32*k;
            float4 xv = *(const float4*)(xrow + p0);                 // 2-way b128: free
            float4 nv = *(const float4*)(sm + LX_INVN + p0);         // broadcast
            int4   lv = *(const int4*)(smi + LX_LABS + p0);
            PROC(xv.x, nv.x, lv.x);
            PROC(xv.y, nv.y, lv.y);
            PROC(xv.z, nv.z, lv.z);
            PROC(xv.w, nv.w, lv.w);
        }
    }

    __syncthreads();

    // --- block reduction: fold 8 subs per d, then global f32 atomics ---
    // reuse sm: red[t][j], stride 39 -> 256*39 = 9984 floats = LTOT exactly
    #pragma unroll
    for (int c = 0; c < CC; c++) {
        sm[t*39 + c]      = aS[c];
        sm[t*39 + 19 + c] = aN[c];
    }
    __syncthreads();
    for (int i = t; i < 32*38; i += NT1) {
        const int dI = i / 38, j = i % 38;
        float s = 0.f;
        #pragma unroll
        for (int su = 0; su < 8; su++) s += sm[(dI*8 + su)*39 + j];
        const int gi = (j < 19) ? (j*CSTRIDE + dI) : ((j - 19)*CSTRIDE + 32 + dI);
        unsafeAtomicAdd(acc + gi, s);
    }
}

// Final: tiny 19-class epilogue. 1 block x 256 threads, deterministic reduction.
__global__ void k3_final(const float* __restrict__ gacc, float* __restrict__ out)
{
    __shared__ float acc[ACCSZ];
    __shared__ float cn[CC];
    __shared__ float pres[CC];
    __shared__ float red[256];
    const int t = threadIdx.x;

    for (int i = t; i < ACCSZ; i += 256) acc[i] = gacc[i];
    __syncthreads();

    float part = 0.f;

    // per-class: norms, presence, sim term
    // cosine is scale-invariant in the center, so raw sums replace centers:
    // seg_cos_c = (sums_c . S_c) / |sums_c|,  S_c = sum_{n in c} x_n/|x_n|
    if (t < CC) {
        const float* a = acc + t * CSTRIDE;
        float n2 = 0.f, dotS = 0.f;
        #pragma unroll
        for (int dd = 0; dd < DD; dd++) {
            n2   = fmaf(a[dd], a[dd], n2);
            dotS = fmaf(a[dd], a[32 + dd], dotS);
        }
        float count = a[64];
        float den   = fmaxf(count, 1.f);
        float norm  = sqrtf(n2);
        cn[t]   = norm;
        pres[t] = (count > 0.f) ? 1.f : 0.f;
        float segcos = (norm > 0.f) ? (dotS / norm) : 0.f;
        part += (count > 0.f) ? (1.f - segcos / den) : 0.f;
    }
    __syncthreads();

    // diff loss: 19x19 pair terms on raw sums (denominators cancel in cosine)
    for (int p = t; p < CC * CC; p += 256) {
        int i = p / CC, j = p % CC;
        const float* ai = acc + i * CSTRIDE;
        const float* aj = acc + j * CSTRIDE;
        float dot = 0.f;
        #pragma unroll
        for (int dd = 0; dd < DD; dd++) dot = fmaf(ai[dd], aj[dd], dot);
        float ddn  = fmaxf(cn[i] * cn[j], EPSF);
        float cs   = dot / ddn;
        float term = (i == j) ? (1.f - cs) : fmaxf(cs, 0.f);
        part += pres[i] * term * (1.f / (float)CC);
    }

    red[t] = part;
    __syncthreads();
    #pragma unroll
    for (int s = 128; s > 0; s >>= 1) {
        if (t < s) red[t] += red[t + s];
        __syncthreads();
    }
    if (t == 0) out[0] = red[0];
}

extern "C" void kernel_launch(void* const* d_in, const int* in_sizes, int n_in,
                              void* d_out, int out_size, void* d_ws, size_t ws_size,
                              hipStream_t stream)
{
    const float* in  = (const float*)d_in[0];
    const int*   tgt = (const int*)d_in[1];   // harness delivers integer inputs as int32
    float* out = (float*)d_out;
    float* acc = (float*)d_ws;                // 1235 floats ~ 5 KB

    hipLaunchKernelGGL(k0_zero,  dim3((ACCSZ + 255) / 256), dim3(256), 0, stream, acc);
    hipLaunchKernelGGL(k_count,  dim3(NCB),  dim3(256), 0, stream, tgt, acc);
    hipLaunchKernelGGL(k1_accum, dim3(NB1),  dim3(256), 0, stream, in, tgt, acc);
    hipLaunchKernelGGL(k3_final, dim3(1),    dim3(256), 0, stream, acc, out);
}

// Round 4
// 642.262 us; speedup vs baseline: 1.2387x; 1.2387x over previous
//
#include <hip/hip_runtime.h>

// Problem constants (fixed by setup_inputs)
#define BB 8
#define DD 32
#define HH 512
#define WW 512
#define HWSZ (HH*WW)          // 262144 = 2^18
#define NPIX (BB*HWSZ)        // 2097152
#define CC 19
#define EPSF 1e-8f

// Global accumulator layout: per class 65 floats:
// [0..31]=sum(x), [32..63]=sum(x/|x|), [64]=count
#define CSTRIDE 65
#define ACCSZ (CC*CSTRIDE)    // 1235 floats

// ---- k1 decomposition ----
// grid 1024 x 256; wave = one 512-pixel cluster (4096 clusters total).
// lane l: dp = l>>2 (dim-pair 0..15 -> dims 2dp,2dp+1), sl = l&3 (pixel quad).
// Per iter k: lane processes pixels p0 + 16k + 4sl .. +4 for its 2 dims.
// Norms finished in-wave via shfl_xor over the 16 dp lanes. No LDS, no barriers
// in the main loop; class masks computed once per pixel, reused for both dims.
#define NT1 256
#define NB1 1024
#define CPB 4                 // clusters (waves) per block
#define CLPX 512              // pixels per cluster
#define KIT (CLPX/16)         // 32 iterations, 16 px per wave-iter

__global__ void k0_zero(float* __restrict__ acc)
{
    int i = blockIdx.x * 256 + threadIdx.x;
    if (i < ACCSZ) acc[i] = 0.f;
}

// ---- tiny label histogram (counts) -> acc[c*65+64] ----
#define NCB 1024
__global__ __launch_bounds__(256) void k_count(const int* __restrict__ tgt,
                                               float* __restrict__ acc)
{
    __shared__ float h[32*20];   // 32 copies x 19 classes (stride 20)
    const int t = threadIdx.x;
    for (int i = t; i < 32*20; i += 256) h[i] = 0.f;
    __syncthreads();
    float* my = h + (t & 31) * 20;
    const int T = NCB * 256;                 // 262144 threads
    int tid = blockIdx.x * 256 + t;
    for (int i = tid; i < NPIX/4; i += T) {  // 2 iterations
        int4 lv = ((const int4*)tgt)[i];
        unsafeAtomicAdd(my + lv.x, 1.f);
        unsafeAtomicAdd(my + lv.y, 1.f);
        unsafeAtomicAdd(my + lv.z, 1.f);
        unsafeAtomicAdd(my + lv.w, 1.f);
    }
    __syncthreads();
    if (t < CC) {
        float s = 0.f;
        #pragma unroll
        for (int k = 0; k < 32; k++) s += h[k*20 + t];
        unsafeAtomicAdd(acc + t*CSTRIDE + 64, s);
    }
}

// One pixel, both dims of the pair: mask computed ONCE, reused 4x.
// float2 accumulators -> SLP can pack the .x/.y fma pairs into v_pk_fma_f32.
#define PROC2(XL, XH, IV, LL)                              \
    {                                                      \
        const float xl_ = (XL), xh_ = (XH);                \
        const float nl_ = xl_ * (IV), nh_ = xh_ * (IV);    \
        const int   l_  = (LL);                            \
        _Pragma("unroll")                                  \
        for (int c = 0; c < CC; c++) {                     \
            const float m_ = (l_ == c) ? 1.0f : 0.0f;      \
            aS[c].x = fmaf(m_, xl_, aS[c].x);              \
            aS[c].y = fmaf(m_, xh_, aS[c].y);              \
            aN[c].x = fmaf(m_, nl_, aN[c].x);              \
            aN[c].y = fmaf(m_, nh_, aN[c].y);              \
        }                                                  \
    }

__global__ __launch_bounds__(NT1, 2) void k1_accum(
    const float* __restrict__ in, const int* __restrict__ tgt,
    float* __restrict__ acc)
{
    __shared__ float red[CPB*16*76];   // 4864 floats = 19456 B (epilogue only)
    const int t  = threadIdx.x;
    const int w  = t >> 6;
    const int l  = t & 63;
    const int dp = l >> 2;             // dim-pair 0..15
    const int sl = l & 3;              // pixel quad 0..3

    float2 aS[CC], aN[CC];
    #pragma unroll
    for (int c = 0; c < CC; c++) {
        aS[c] = make_float2(0.f, 0.f);
        aN[c] = make_float2(0.f, 0.f);
    }

    const int cluster = (blockIdx.x << 2) | w;   // 0..4095
    const int p0 = cluster << 9;                 // *CLPX
    const int b  = p0 >> 18;                     // batch image (512 | HWSZ)
    const int hw = p0 & (HWSZ - 1);

    const float* pl = in + ((size_t)(b*DD + 2*dp))*HWSZ + hw + 4*sl;
    const float* ph = pl + HWSZ;
    const int*   pt = tgt + p0 + 4*sl;

    #pragma unroll 1
    for (int k = 0; k < KIT; k++) {
        const int o = 16*k;
        float4 xl = *(const float4*)(pl + o);    // dim 2dp,   4 px (64B/4-lane seg)
        float4 xh = *(const float4*)(ph + o);    // dim 2dp+1, 4 px
        int4   lv = *(const int4*)(pt + o);      // labels (16-lane broadcast)

        // per-pixel partial squared sums over this lane's 2 dims
        float4 ss;
        ss.x = fmaf(xl.x, xl.x, xh.x*xh.x);
        ss.y = fmaf(xl.y, xl.y, xh.y*xh.y);
        ss.z = fmaf(xl.z, xl.z, xh.z*xh.z);
        ss.w = fmaf(xl.w, xl.w, xh.w*xh.w);
        // butterfly over the 16 dp lanes (masks 4,8,16,32) -> full 32-dim sums
        #pragma unroll
        for (int m = 4; m <= 32; m <<= 1) {
            ss.x += __shfl_xor(ss.x, m);
            ss.y += __shfl_xor(ss.y, m);
            ss.z += __shfl_xor(ss.z, m);
            ss.w += __shfl_xor(ss.w, m);
        }
        float4 iv;
        iv.x = rsqrtf(fmaxf(ss.x, 1e-30f));
        iv.y = rsqrtf(fmaxf(ss.y, 1e-30f));
        iv.z = rsqrtf(fmaxf(ss.z, 1e-30f));
        iv.w = rsqrtf(fmaxf(ss.w, 1e-30f));

        PROC2(xl.x, xh.x, iv.x, lv.x);
        PROC2(xl.y, xh.y, iv.y, lv.y);
        PROC2(xl.z, xh.z, iv.z, lv.z);
        PROC2(xl.w, xh.w, iv.w, lv.w);
    }

    // ---- in-wave fold over the 4 sl lanes sharing each dp (masks 1,2) ----
    #pragma unroll
    for (int c = 0; c < CC; c++) {
        aS[c].x += __shfl_xor(aS[c].x, 1); aS[c].x += __shfl_xor(aS[c].x, 2);
        aS[c].y += __shfl_xor(aS[c].y, 1); aS[c].y += __shfl_xor(aS[c].y, 2);
        aN[c].x += __shfl_xor(aN[c].x, 1); aN[c].x += __shfl_xor(aN[c].x, 2);
        aN[c].y += __shfl_xor(aN[c].y, 1); aN[c].y += __shfl_xor(aN[c].y, 2);
    }
    if (sl == 0) {
        float* dst = red + (w*16 + dp)*76;
        #pragma unroll
        for (int c = 0; c < CC; c++) {
            dst[c]      = aS[c].x;
            dst[19 + c] = aS[c].y;
            dst[38 + c] = aN[c].x;
            dst[57 + c] = aN[c].y;
        }
    }
    __syncthreads();

    // ---- fold 4 wave copies, one global f32 atomic per (class,dim,kind) ----
    for (int i = t; i < 16*76; i += NT1) {
        float s = red[i] + red[1216 + i] + red[2432 + i] + red[3648 + i];
        const int dpi = i / 76, j = i % 76;
        const int c = j % 19, part = j / 19;          // 0:S.lo 1:S.hi 2:N.lo 3:N.hi
        const int gi = c*CSTRIDE + 2*dpi + (part & 1) + ((part >= 2) ? 32 : 0);
        unsafeAtomicAdd(acc + gi, s);
    }
}

// Final: tiny 19-class epilogue. 1 block x 256 threads, deterministic reduction.
__global__ void k3_final(const float* __restrict__ gacc, float* __restrict__ out)
{
    __shared__ float acc[ACCSZ];
    __shared__ float cn[CC];
    __shared__ float pres[CC];
    __shared__ float red[256];
    const int t = threadIdx.x;

    for (int i = t; i < ACCSZ; i += 256) acc[i] = gacc[i];
    __syncthreads();

    float part = 0.f;

    // per-class: norms, presence, sim term.
    // cosine is scale-invariant in the center, so raw sums replace centers:
    // seg_cos_c = (sums_c . S_c) / |sums_c|,  S_c = sum_{n in c} x_n/|x_n|
    if (t < CC) {
        const float* a = acc + t * CSTRIDE;
        float n2 = 0.f, dotS = 0.f;
        #pragma unroll
        for (int dd = 0; dd < DD; dd++) {
            n2   = fmaf(a[dd], a[dd], n2);
            dotS = fmaf(a[dd], a[32 + dd], dotS);
        }
        float count = a[64];
        float den   = fmaxf(count, 1.f);
        float norm  = sqrtf(n2);
        cn[t]   = norm;
        pres[t] = (count > 0.f) ? 1.f : 0.f;
        float segcos = (norm > 0.f) ? (dotS / norm) : 0.f;
        part += (count > 0.f) ? (1.f - segcos / den) : 0.f;
    }
    __syncthreads();

    // diff loss: 19x19 pair terms on raw sums (denominators cancel in cosine)
    for (int p = t; p < CC * CC; p += 256) {
        int i = p / CC, j = p % CC;
        const float* ai = acc + i * CSTRIDE;
        const float* aj = acc + j * CSTRIDE;
        float dot = 0.f;
        #pragma unroll
        for (int dd = 0; dd < DD; dd++) dot = fmaf(ai[dd], aj[dd], dot);
        float ddn  = fmaxf(cn[i] * cn[j], EPSF);
        float cs   = dot / ddn;
        float term = (i == j) ? (1.f - cs) : fmaxf(cs, 0.f);
        part += pres[i] * term * (1.f / (float)CC);
    }

    red[t] = part;
    __syncthreads();
    #pragma unroll
    for (int s = 128; s > 0; s >>= 1) {
        if (t < s) red[t] += red[t + s];
        __syncthreads();
    }
    if (t == 0) out[0] = red[0];
}

extern "C" void kernel_launch(void* const* d_in, const int* in_sizes, int n_in,
                              void* d_out, int out_size, void* d_ws, size_t ws_size,
                              hipStream_t stream)
{
    const float* in  = (const float*)d_in[0];
    const int*   tgt = (const int*)d_in[1];   // harness delivers integer inputs as int32
    float* out = (float*)d_out;
    float* acc = (float*)d_ws;                // 1235 floats ~ 5 KB

    hipLaunchKernelGGL(k0_zero,  dim3((ACCSZ + 255) / 256), dim3(256), 0, stream, acc);
    hipLaunchKernelGGL(k_count,  dim3(NCB),  dim3(256), 0, stream, tgt, acc);
    hipLaunchKernelGGL(k1_accum, dim3(NB1),  dim3(256), 0, stream, in, tgt, acc);
    hipLaunchKernelGGL(k3_final, dim3(1),    dim3(256), 0, stream, acc, out);
}